// Round 8
// baseline (197.966 us; speedup 1.0000x reference)
//
#include <hip/hip_runtime.h>
#include <hip/hip_bf16.h>
#include <stdint.h>

// LocalSlidingWindowAttention: B=2, T=2048, D=1024, H=16, hd=64, keys j in [i, i+64].
// f32 in/out. convert_all -> gemm1 (128x256 tile) -> attn_mfma -> gemm2 (64x128).
// Model (r7): gemm1 is staging-BW-bound (~44 B/cyc/CU global->LDS). Bigger tile cuts
// staged bytes/FLOP 25% (393->295 MB). gemm2: 512 blocks = 2/CU for drain overlap.

typedef short bf16x8 __attribute__((ext_vector_type(8)));
typedef float f32x4 __attribute__((ext_vector_type(4)));

typedef const __attribute__((address_space(1))) void* gptr_t;
typedef __attribute__((address_space(3))) void* lptr_t;

__device__ __forceinline__ float bf2f(short u) {
    union { float f; uint32_t i; } x;
    x.i = ((uint32_t)(uint16_t)u) << 16;
    return x.f;
}
__device__ __forceinline__ short f2bf(float f) {
    __hip_bfloat16 h = __float2bfloat16(f);  // RNE
    return *reinterpret_cast<short*>(&h);
}

// Convert x, w_qkv, w_out to bf16. 8 elems/thread.
__global__ __launch_bounds__(256)
void convert_all(const float* __restrict__ x, const float* __restrict__ wq,
                 const float* __restrict__ wo,
                 short* __restrict__ xb, short* __restrict__ wqb, short* __restrict__ wob) {
    int i = blockIdx.x * 256 + threadIdx.x;
    const float* src; short* dst; int o;
    if      (i <  524288) { src = x;  dst = xb;  o = i; }
    else if (i <  917504) { src = wq; dst = wqb; o = i - 524288; }
    else                  { src = wo; dst = wob; o = i - 917504; }
    const int e = o * 8;
    float4 a = *(const float4*)(src + e);
    float4 b = *(const float4*)(src + e + 4);
    short t[8];
    t[0] = f2bf(a.x); t[1] = f2bf(a.y); t[2] = f2bf(a.z); t[3] = f2bf(a.w);
    t[4] = f2bf(b.x); t[5] = f2bf(b.y); t[6] = f2bf(b.z); t[7] = f2bf(b.w);
    *(uint4*)(dst + e) = *(const uint4*)t;
}

// GEMM1: C[m,n] = sum_k A[m,k]*Bt[n,k] + bias[n], bf16 out, f32 bias.
// Tile 128(m) x 256(n), BK=32. 4 waves as 2x2; each wave 64 rows x 128 cols
// (acc[4][8] ~ 160 VGPR -> 2 blocks/CU at 48 KB LDS). Staged 24 KB / 2.1 MFLOP.
__global__ __launch_bounds__(256)
void gemm1_qkv(const short* __restrict__ A, const short* __restrict__ Bt,
               const float* __restrict__ bias, short* __restrict__ C,
               int M, int N, int K) {
    __shared__ short As[128 * 32];   // 8 KB  (unpadded: global_load_lds lane layout)
    __shared__ short Bs[256 * 32];   // 16 KB

    const int tid  = threadIdx.x;
    const int lane = tid & 63;
    const int w    = tid >> 6;
    const int qd   = lane >> 4;
    const int l16  = lane & 15;
    const int wm   = w >> 1;          // 0..1 -> 64 rows
    const int wn   = w & 1;           // 0..1 -> 128 cols
    const int mBase = blockIdx.y * 128;
    const int nBase = blockIdx.x * 256;

    f32x4 acc[4][8] = {};

    const int nK = K >> 5;
    for (int kt = 0; kt < nK; ++kt) {
        const int kb = kt << 5;
#pragma unroll
        for (int i = 0; i < 2; ++i) {           // A: 128x32 = 2 chunk-rounds
            const int e   = i * 2048 + tid * 8;
            const int row = e >> 5;
            const int col = e & 31;
            const short* ga = A + (size_t)(mBase + row) * K + kb + col;
            lptr_t la = (lptr_t)(As + i * 2048 + w * 512);
            __builtin_amdgcn_global_load_lds((gptr_t)ga, la, 16, 0, 0);
        }
#pragma unroll
        for (int i = 0; i < 4; ++i) {           // B: 256x32 = 4 chunk-rounds
            const int e   = i * 2048 + tid * 8;
            const int row = e >> 5;
            const int col = e & 31;
            const short* gb = Bt + (size_t)(nBase + row) * K + kb + col;
            lptr_t lb = (lptr_t)(Bs + i * 2048 + w * 512);
            __builtin_amdgcn_global_load_lds((gptr_t)gb, lb, 16, 0, 0);
        }
        __syncthreads();

        bf16x8 af[4], bfr[8];
#pragma unroll
        for (int mi = 0; mi < 4; ++mi)
            af[mi] = *(const bf16x8*)(As + (wm * 64 + mi * 16 + l16) * 32 + qd * 8);
#pragma unroll
        for (int ni = 0; ni < 8; ++ni)
            bfr[ni] = *(const bf16x8*)(Bs + (wn * 128 + ni * 16 + l16) * 32 + qd * 8);
#pragma unroll
        for (int mi = 0; mi < 4; ++mi)
#pragma unroll
            for (int ni = 0; ni < 8; ++ni)
                acc[mi][ni] = __builtin_amdgcn_mfma_f32_16x16x32_bf16(
                    af[mi], bfr[ni], acc[mi][ni], 0, 0, 0);
        __syncthreads();
    }

    // C-layout: n = ..+l16 (lane-consecutive), m = ..+qd*4+r.
#pragma unroll
    for (int ni = 0; ni < 8; ++ni) {
        const int n = nBase + wn * 128 + ni * 16 + l16;
        const float bv = bias[n];
#pragma unroll
        for (int mi = 0; mi < 4; ++mi)
#pragma unroll
            for (int rr = 0; rr < 4; ++rr) {
                const int m = mBase + wm * 64 + mi * 16 + qd * 4 + rr;
                C[(size_t)m * N + n] = f2bf(acc[mi][ni][rr] + bv);
            }
    }
}

// GEMM2: out = attn @ w_out^T + b_out, f32 out/bias. 64x128 tile, BK=32.
// Grid (8,64) = 512 blocks = 2/CU (12 KB LDS) -> barrier drains overlap across blocks.
__global__ __launch_bounds__(256)
void gemm2_out(const short* __restrict__ A, const short* __restrict__ Bt,
               const float* __restrict__ bias, float* __restrict__ C,
               int M, int N, int K) {
    __shared__ short As[64 * 32];    // 4 KB
    __shared__ short Bs[128 * 32];   // 8 KB

    const int tid  = threadIdx.x;
    const int lane = tid & 63;
    const int w    = tid >> 6;
    const int qd   = lane >> 4;
    const int l16  = lane & 15;
    const int wm   = w >> 1;          // 32 rows each
    const int wn   = w & 1;           // 64 cols each
    const int mBase = blockIdx.y * 64;
    const int nBase = blockIdx.x * 128;

    f32x4 acc[2][4] = {};

    const int nK = K >> 5;
    for (int kt = 0; kt < nK; ++kt) {
        const int kb = kt << 5;
        {
            const int e   = tid * 8;            // A: 64x32, one chunk-round
            const int row = e >> 5;
            const int col = e & 31;
            const short* ga = A + (size_t)(mBase + row) * K + kb + col;
            lptr_t la = (lptr_t)(As + w * 512);
            __builtin_amdgcn_global_load_lds((gptr_t)ga, la, 16, 0, 0);
        }
#pragma unroll
        for (int i = 0; i < 2; ++i) {           // B: 128x32
            const int e   = i * 2048 + tid * 8;
            const int row = e >> 5;
            const int col = e & 31;
            const short* gb = Bt + (size_t)(nBase + row) * K + kb + col;
            lptr_t lb = (lptr_t)(Bs + i * 2048 + w * 512);
            __builtin_amdgcn_global_load_lds((gptr_t)gb, lb, 16, 0, 0);
        }
        __syncthreads();

        bf16x8 af[2], bfr[4];
#pragma unroll
        for (int mi = 0; mi < 2; ++mi)
            af[mi] = *(const bf16x8*)(As + (wm * 32 + mi * 16 + l16) * 32 + qd * 8);
#pragma unroll
        for (int ni = 0; ni < 4; ++ni)
            bfr[ni] = *(const bf16x8*)(Bs + (wn * 64 + ni * 16 + l16) * 32 + qd * 8);
#pragma unroll
        for (int mi = 0; mi < 2; ++mi)
#pragma unroll
            for (int ni = 0; ni < 4; ++ni)
                acc[mi][ni] = __builtin_amdgcn_mfma_f32_16x16x32_bf16(
                    af[mi], bfr[ni], acc[mi][ni], 0, 0, 0);
        __syncthreads();
    }

#pragma unroll
    for (int ni = 0; ni < 4; ++ni) {
        const int n = nBase + wn * 64 + ni * 16 + l16;
        const float bv = bias[n];
#pragma unroll
        for (int mi = 0; mi < 2; ++mi)
#pragma unroll
            for (int rr = 0; rr < 4; ++rr) {
                const int m = mBase + wm * 32 + mi * 16 + qd * 4 + rr;
                C[(size_t)m * N + n] = acc[mi][ni][rr] + bv;
            }
    }
}

// MFMA attention (unchanged — proven). Block = 64 queries x head x batch.
__global__ __launch_bounds__(256)
void attn_mfma(const short* __restrict__ qkv, short* __restrict__ attn_out, int B, int T) {
    __shared__ short k_s[128 * 72];
    __shared__ short v_s[144 * 66];
    __shared__ short p_s[64 * 104];

    const int tid  = threadIdx.x;
    const int lane = tid & 63;
    const int w    = tid >> 6;
    const int qd   = lane >> 4;
    const int l16  = lane & 15;
    const int qs   = blockIdx.x * 64;
    const int h    = blockIdx.y;
    const int b    = blockIdx.z;
    const size_t rs   = 3072;
    const size_t base = (size_t)b * T * rs;
    const int qoff = h * 64, koff = 1024 + h * 64, voff = 2048 + h * 64;

#pragma unroll
    for (int i = 0; i < 5; ++i) {
        const int c   = tid + i * 256;
        const int row = c >> 3;
        if (row >= 144) break;
        const int ch = (c & 7) * 8;
        int gr = qs + row; if (gr > T - 1) gr = T - 1;
        uint4 uv = *(const uint4*)(qkv + base + (size_t)gr * rs + voff + ch);
        if (row < 128) {
            uint4 uk = *(const uint4*)(qkv + base + (size_t)gr * rs + koff + ch);
            *(uint4*)&k_s[row * 72 + ch] = uk;
        }
        const uint32_t* vp = (const uint32_t*)&uv;
        uint32_t* vd = (uint32_t*)&v_s[row * 66 + ch];
        vd[0] = vp[0]; vd[1] = vp[1]; vd[2] = vp[2]; vd[3] = vp[3];
    }
    __syncthreads();

    bf16x8 aq0, aq1;
    {
        const short* g = qkv + base + (size_t)(qs + 16 * w + l16) * rs + qoff + qd * 8;
        aq0 = *(const bf16x8*)(g);
        aq1 = *(const bf16x8*)(g + 32);
    }

    f32x4 sacc[5] = {};
#pragma unroll
    for (int u = 0; u < 5; ++u) {
        const int krow = 16 * (w + u) + l16;
        bf16x8 bk0 = *(const bf16x8*)&k_s[krow * 72 + qd * 8];
        bf16x8 bk1 = *(const bf16x8*)&k_s[krow * 72 + 32 + qd * 8];
        sacc[u] = __builtin_amdgcn_mfma_f32_16x16x32_bf16(aq0, bk0, sacc[u], 0, 0, 0);
        sacc[u] = __builtin_amdgcn_mfma_f32_16x16x32_bf16(aq1, bk1, sacc[u], 0, 0, 0);
    }

    const float scale = 0.125f;
    float pw[5][4];
    float inv[4];
#pragma unroll
    for (int r = 0; r < 4; ++r) {
        const int m = 4 * qd + r;
        float mx = -3.4e38f;
#pragma unroll
        for (int u = 0; u < 5; ++u) {
            const int rel = 16 * u + l16 - m;
            const int j   = qs + 16 * (w + u) + l16;
            const bool ok = (rel >= 0) & (rel <= 64) & (j < T);
            const float v = ok ? sacc[u][r] * scale : -3.4e38f;
            pw[u][r] = v;
            mx = fmaxf(mx, v);
        }
#pragma unroll
        for (int msk = 1; msk <= 8; msk <<= 1) mx = fmaxf(mx, __shfl_xor(mx, msk));
        float sum = 0.f;
#pragma unroll
        for (int u = 0; u < 5; ++u) {
            float e = (pw[u][r] <= -3.0e38f) ? 0.f : __expf(pw[u][r] - mx);
            pw[u][r] = e;
            sum += e;
        }
#pragma unroll
        for (int msk = 1; msk <= 8; msk <<= 1) sum += __shfl_xor(sum, msk);
        inv[r] = 1.0f / sum;
    }

#pragma unroll
    for (int u = 0; u < 5; ++u)
#pragma unroll
        for (int r = 0; r < 4; ++r)
            p_s[(16 * w + 4 * qd + r) * 104 + 16 * u + l16] = f2bf(pw[u][r] * inv[r]);
#pragma unroll
    for (int r = 0; r < 4; ++r)
        p_s[(16 * w + 4 * qd + r) * 104 + 80 + l16] = 0;
    // wave-private rows; same-wave RAW -> lgkmcnt wait, no barrier needed

    f32x4 oacc[4] = {};
#pragma unroll
    for (int ks = 0; ks < 3; ++ks) {
        bf16x8 ap = *(const bf16x8*)&p_s[(16 * w + l16) * 104 + ks * 32 + qd * 8];
#pragma unroll
        for (int dt = 0; dt < 4; ++dt) {
            short t[8];
#pragma unroll
            for (int j = 0; j < 8; ++j)
                t[j] = v_s[(16 * w + ks * 32 + qd * 8 + j) * 66 + 16 * dt + l16];
            bf16x8 bv = *(const bf16x8*)t;
            oacc[dt] = __builtin_amdgcn_mfma_f32_16x16x32_bf16(bv, ap, oacc[dt], 0, 0, 0);
        }
    }

    const size_t row = (size_t)(b * T + qs + 16 * w + l16);
#pragma unroll
    for (int dt = 0; dt < 4; ++dt) {
        short t[4];
#pragma unroll
        for (int r = 0; r < 4; ++r) t[r] = f2bf(oacc[dt][r]);
        *(uint2*)&attn_out[row * 1024 + h * 64 + dt * 16 + qd * 4] = *(const uint2*)t;
    }
}

extern "C" void kernel_launch(void* const* d_in, const int* in_sizes, int n_in,
                              void* d_out, int out_size, void* d_ws, size_t ws_size,
                              hipStream_t stream) {
    (void)in_sizes; (void)n_in; (void)out_size; (void)ws_size;
    const int B = 2, T = 2048, D = 1024;
    const int M = B * T;  // 4096

    char* ws = (char*)d_ws;
    size_t off = 0;
    short* xb   = (short*)(ws + off); off += (size_t)M * D * 2;       // 8.4 MB
    short* wqkb = (short*)(ws + off); off += (size_t)3 * D * D * 2;   // 6.3 MB
    short* wob  = (short*)(ws + off); off += (size_t)D * D * 2;       // 2.1 MB
    short* qkv  = (short*)(ws + off); off += (size_t)M * 3 * D * 2;   // 25.2 MB
    short* attn = (short*)(ws + off); off += (size_t)M * D * 2;       // 8.4 MB

    convert_all<<<dim3(4096), 256, 0, stream>>>(
        (const float*)d_in[0], (const float*)d_in[1], (const float*)d_in[3],
        xb, wqkb, wob);

    gemm1_qkv<<<dim3(3 * D / 256, M / 128), 256, 0, stream>>>(
        xb, wqkb, (const float*)d_in[2], qkv, M, 3 * D, D);
    attn_mfma<<<dim3(T / 64, 16, B), 256, 0, stream>>>(qkv, attn, B, T);
    gemm2_out<<<dim3(D / 128, M / 64), 256, 0, stream>>>(
        attn, wob, (const float*)d_in[4], (float*)d_out, M, D, D);
}

// Round 9
// 158.194 us; speedup vs baseline: 1.2514x; 1.2514x over previous
//
#include <hip/hip_runtime.h>
#include <hip/hip_bf16.h>
#include <stdint.h>

// LocalSlidingWindowAttention: B=2, T=2048, D=1024, H=16, hd=64, keys j in [i, i+64].
// f32 in/out. Best-of-components build:
//   convert_all (r7) -> gemm1_qkv (r7: 128x128, BK=32, 768-block flat grid, 3/CU)
//   -> attn_mfma (r3, proven) -> gemm2_out (r8: 64x128, BK=32, 512 blocks = 2/CU).
// Session model: total ~= kernels + ~85us fixed harness overhead (ws poison 44us + restores).
// r8 cross-check: gemm2@2blocks/CU saves ~13us vs 1/CU (drain overlap, m114 mechanism).

typedef short bf16x8 __attribute__((ext_vector_type(8)));
typedef float f32x4 __attribute__((ext_vector_type(4)));

typedef const __attribute__((address_space(1))) void* gptr_t;
typedef __attribute__((address_space(3))) void* lptr_t;

__device__ __forceinline__ float bf2f(short u) {
    union { float f; uint32_t i; } x;
    x.i = ((uint32_t)(uint16_t)u) << 16;
    return x.f;
}
__device__ __forceinline__ short f2bf(float f) {
    __hip_bfloat16 h = __float2bfloat16(f);  // RNE
    return *reinterpret_cast<short*>(&h);
}

// Convert x, w_qkv, w_out to bf16. 8 elems/thread.
__global__ __launch_bounds__(256)
void convert_all(const float* __restrict__ x, const float* __restrict__ wq,
                 const float* __restrict__ wo,
                 short* __restrict__ xb, short* __restrict__ wqb, short* __restrict__ wob) {
    int i = blockIdx.x * 256 + threadIdx.x;
    const float* src; short* dst; int o;
    if      (i <  524288) { src = x;  dst = xb;  o = i; }
    else if (i <  917504) { src = wq; dst = wqb; o = i - 524288; }
    else                  { src = wo; dst = wob; o = i - 917504; }
    const int e = o * 8;
    float4 a = *(const float4*)(src + e);
    float4 b = *(const float4*)(src + e + 4);
    short t[8];
    t[0] = f2bf(a.x); t[1] = f2bf(a.y); t[2] = f2bf(a.z); t[3] = f2bf(a.w);
    t[4] = f2bf(b.x); t[5] = f2bf(b.y); t[6] = f2bf(b.z); t[7] = f2bf(b.w);
    *(uint4*)(dst + e) = *(const uint4*)t;
}

// GEMM1 (r7 proven, 43.7us): C[m,n] = sum_k A[m,k]*Bt[n,k] + bias[n], bf16 out, f32 bias.
// 128x128, BK=32. Flat grid 768 (3 blocks/CU exact), XCD-grouped n-tiles.
__global__ __launch_bounds__(256)
void gemm1_qkv(const short* __restrict__ A, const short* __restrict__ Bt,
               const float* __restrict__ bias, short* __restrict__ C,
               int M, int N, int K) {
    __shared__ short As[128 * 32];  // unpadded: required by global_load_lds lane layout
    __shared__ short Bs[128 * 32];

    const int bid = blockIdx.x;
    const int g   = bid & 7;          // XCD (dispatch round-robin %8)
    const int r   = bid >> 3;         // 0..95
    const int xt  = g + 8 * (r % 3);  // n-tile 0..23
    const int yt  = r / 3;            // m-tile 0..31

    const int tid  = threadIdx.x;
    const int lane = tid & 63;
    const int w    = tid >> 6;
    const int qd   = lane >> 4;
    const int l16  = lane & 15;
    const int wm   = w >> 1;
    const int wn   = w & 1;
    const int mBase = yt * 128;
    const int nBase = xt * 128;

    f32x4 acc[4][4] = {};

    const int nK = K >> 5;
    for (int kt = 0; kt < nK; ++kt) {
        const int kb = kt << 5;
#pragma unroll
        for (int i = 0; i < 2; ++i) {
            const int e   = i * 2048 + tid * 8;
            const int row = e >> 5;
            const int col = e & 31;
            const short* ga = A  + (size_t)(mBase + row) * K + kb + col;
            const short* gb = Bt + (size_t)(nBase + row) * K + kb + col;
            lptr_t la = (lptr_t)(As + i * 2048 + w * 512);
            lptr_t lb = (lptr_t)(Bs + i * 2048 + w * 512);
            __builtin_amdgcn_global_load_lds((gptr_t)ga, la, 16, 0, 0);
            __builtin_amdgcn_global_load_lds((gptr_t)gb, lb, 16, 0, 0);
        }
        __syncthreads();

        bf16x8 af[4], bfr[4];
#pragma unroll
        for (int mi = 0; mi < 4; ++mi)
            af[mi] = *(const bf16x8*)(As + (wm * 64 + mi * 16 + l16) * 32 + qd * 8);
#pragma unroll
        for (int ni = 0; ni < 4; ++ni)
            bfr[ni] = *(const bf16x8*)(Bs + (wn * 64 + ni * 16 + l16) * 32 + qd * 8);
#pragma unroll
        for (int mi = 0; mi < 4; ++mi)
#pragma unroll
            for (int ni = 0; ni < 4; ++ni)
                acc[mi][ni] = __builtin_amdgcn_mfma_f32_16x16x32_bf16(
                    af[mi], bfr[ni], acc[mi][ni], 0, 0, 0);
        __syncthreads();
    }

    // C-layout: n = ..+l16 (lane-consecutive -> 128B segments), m = ..+qd*4+r.
#pragma unroll
    for (int ni = 0; ni < 4; ++ni) {
        const int n = nBase + wn * 64 + ni * 16 + l16;
        const float bv = bias[n];
#pragma unroll
        for (int mi = 0; mi < 4; ++mi)
#pragma unroll
            for (int rr = 0; rr < 4; ++rr) {
                const int m = mBase + wm * 64 + mi * 16 + qd * 4 + rr;
                C[(size_t)m * N + n] = f2bf(acc[mi][ni][rr] + bv);
            }
    }
}

// GEMM2 (r8 proven component): out = attn @ w_out^T + b_out, f32 out/bias.
// 64x128 tile, BK=32. Grid (8,64) = 512 blocks = 2/CU (12 KB LDS) -> drain overlap.
__global__ __launch_bounds__(256)
void gemm2_out(const short* __restrict__ A, const short* __restrict__ Bt,
               const float* __restrict__ bias, float* __restrict__ C,
               int M, int N, int K) {
    __shared__ short As[64 * 32];    // 4 KB
    __shared__ short Bs[128 * 32];   // 8 KB

    const int tid  = threadIdx.x;
    const int lane = tid & 63;
    const int w    = tid >> 6;
    const int qd   = lane >> 4;
    const int l16  = lane & 15;
    const int wm   = w >> 1;          // 32 rows each
    const int wn   = w & 1;           // 64 cols each
    const int mBase = blockIdx.y * 64;
    const int nBase = blockIdx.x * 128;

    f32x4 acc[2][4] = {};

    const int nK = K >> 5;
    for (int kt = 0; kt < nK; ++kt) {
        const int kb = kt << 5;
        {
            const int e   = tid * 8;            // A: 64x32, one chunk-round
            const int row = e >> 5;
            const int col = e & 31;
            const short* ga = A + (size_t)(mBase + row) * K + kb + col;
            lptr_t la = (lptr_t)(As + w * 512);
            __builtin_amdgcn_global_load_lds((gptr_t)ga, la, 16, 0, 0);
        }
#pragma unroll
        for (int i = 0; i < 2; ++i) {           // B: 128x32
            const int e   = i * 2048 + tid * 8;
            const int row = e >> 5;
            const int col = e & 31;
            const short* gb = Bt + (size_t)(nBase + row) * K + kb + col;
            lptr_t lb = (lptr_t)(Bs + i * 2048 + w * 512);
            __builtin_amdgcn_global_load_lds((gptr_t)gb, lb, 16, 0, 0);
        }
        __syncthreads();

        bf16x8 af[2], bfr[4];
#pragma unroll
        for (int mi = 0; mi < 2; ++mi)
            af[mi] = *(const bf16x8*)(As + (wm * 32 + mi * 16 + l16) * 32 + qd * 8);
#pragma unroll
        for (int ni = 0; ni < 4; ++ni)
            bfr[ni] = *(const bf16x8*)(Bs + (wn * 64 + ni * 16 + l16) * 32 + qd * 8);
#pragma unroll
        for (int mi = 0; mi < 2; ++mi)
#pragma unroll
            for (int ni = 0; ni < 4; ++ni)
                acc[mi][ni] = __builtin_amdgcn_mfma_f32_16x16x32_bf16(
                    af[mi], bfr[ni], acc[mi][ni], 0, 0, 0);
        __syncthreads();
    }

#pragma unroll
    for (int ni = 0; ni < 4; ++ni) {
        const int n = nBase + wn * 64 + ni * 16 + l16;
        const float bv = bias[n];
#pragma unroll
        for (int mi = 0; mi < 2; ++mi)
#pragma unroll
            for (int rr = 0; rr < 4; ++rr) {
                const int m = mBase + wm * 32 + mi * 16 + qd * 4 + rr;
                C[(size_t)m * N + n] = acc[mi][ni][rr] + bv;
            }
    }
}

// MFMA attention (r3, proven). Block = 64 queries x head x batch; 4 waves.
__global__ __launch_bounds__(256)
void attn_mfma(const short* __restrict__ qkv, short* __restrict__ attn_out, int B, int T) {
    __shared__ short k_s[128 * 72];
    __shared__ short v_s[144 * 66];
    __shared__ short p_s[64 * 104];

    const int tid  = threadIdx.x;
    const int lane = tid & 63;
    const int w    = tid >> 6;
    const int qd   = lane >> 4;
    const int l16  = lane & 15;
    const int qs   = blockIdx.x * 64;
    const int h    = blockIdx.y;
    const int b    = blockIdx.z;
    const size_t rs   = 3072;
    const size_t base = (size_t)b * T * rs;
    const int qoff = h * 64, koff = 1024 + h * 64, voff = 2048 + h * 64;

#pragma unroll
    for (int i = 0; i < 5; ++i) {
        const int c   = tid + i * 256;
        const int row = c >> 3;
        if (row >= 144) break;
        const int ch = (c & 7) * 8;
        int gr = qs + row; if (gr > T - 1) gr = T - 1;
        uint4 uv = *(const uint4*)(qkv + base + (size_t)gr * rs + voff + ch);
        if (row < 128) {
            uint4 uk = *(const uint4*)(qkv + base + (size_t)gr * rs + koff + ch);
            *(uint4*)&k_s[row * 72 + ch] = uk;
        }
        const uint32_t* vp = (const uint32_t*)&uv;
        uint32_t* vd = (uint32_t*)&v_s[row * 66 + ch];
        vd[0] = vp[0]; vd[1] = vp[1]; vd[2] = vp[2]; vd[3] = vp[3];
    }
    __syncthreads();

    bf16x8 aq0, aq1;
    {
        const short* g = qkv + base + (size_t)(qs + 16 * w + l16) * rs + qoff + qd * 8;
        aq0 = *(const bf16x8*)(g);
        aq1 = *(const bf16x8*)(g + 32);
    }

    f32x4 sacc[5] = {};
#pragma unroll
    for (int u = 0; u < 5; ++u) {
        const int krow = 16 * (w + u) + l16;
        bf16x8 bk0 = *(const bf16x8*)&k_s[krow * 72 + qd * 8];
        bf16x8 bk1 = *(const bf16x8*)&k_s[krow * 72 + 32 + qd * 8];
        sacc[u] = __builtin_amdgcn_mfma_f32_16x16x32_bf16(aq0, bk0, sacc[u], 0, 0, 0);
        sacc[u] = __builtin_amdgcn_mfma_f32_16x16x32_bf16(aq1, bk1, sacc[u], 0, 0, 0);
    }

    const float scale = 0.125f;
    float pw[5][4];
    float inv[4];
#pragma unroll
    for (int r = 0; r < 4; ++r) {
        const int m = 4 * qd + r;
        float mx = -3.4e38f;
#pragma unroll
        for (int u = 0; u < 5; ++u) {
            const int rel = 16 * u + l16 - m;
            const int j   = qs + 16 * (w + u) + l16;
            const bool ok = (rel >= 0) & (rel <= 64) & (j < T);
            const float v = ok ? sacc[u][r] * scale : -3.4e38f;
            pw[u][r] = v;
            mx = fmaxf(mx, v);
        }
#pragma unroll
        for (int msk = 1; msk <= 8; msk <<= 1) mx = fmaxf(mx, __shfl_xor(mx, msk));
        float sum = 0.f;
#pragma unroll
        for (int u = 0; u < 5; ++u) {
            float e = (pw[u][r] <= -3.0e38f) ? 0.f : __expf(pw[u][r] - mx);
            pw[u][r] = e;
            sum += e;
        }
#pragma unroll
        for (int msk = 1; msk <= 8; msk <<= 1) sum += __shfl_xor(sum, msk);
        inv[r] = 1.0f / sum;
    }

#pragma unroll
    for (int u = 0; u < 5; ++u)
#pragma unroll
        for (int r = 0; r < 4; ++r)
            p_s[(16 * w + 4 * qd + r) * 104 + 16 * u + l16] = f2bf(pw[u][r] * inv[r]);
#pragma unroll
    for (int r = 0; r < 4; ++r)
        p_s[(16 * w + 4 * qd + r) * 104 + 80 + l16] = 0;
    // wave-private rows; same-wave RAW -> lgkmcnt wait, no barrier needed

    f32x4 oacc[4] = {};
#pragma unroll
    for (int ks = 0; ks < 3; ++ks) {
        bf16x8 ap = *(const bf16x8*)&p_s[(16 * w + l16) * 104 + ks * 32 + qd * 8];
#pragma unroll
        for (int dt = 0; dt < 4; ++dt) {
            short t[8];
#pragma unroll
            for (int j = 0; j < 8; ++j)
                t[j] = v_s[(16 * w + ks * 32 + qd * 8 + j) * 66 + 16 * dt + l16];
            bf16x8 bv = *(const bf16x8*)t;
            oacc[dt] = __builtin_amdgcn_mfma_f32_16x16x32_bf16(bv, ap, oacc[dt], 0, 0, 0);
        }
    }

    const size_t row = (size_t)(b * T + qs + 16 * w + l16);
#pragma unroll
    for (int dt = 0; dt < 4; ++dt) {
        short t[4];
#pragma unroll
        for (int r = 0; r < 4; ++r) t[r] = f2bf(oacc[dt][r]);
        *(uint2*)&attn_out[row * 1024 + h * 64 + dt * 16 + qd * 4] = *(const uint2*)t;
    }
}

extern "C" void kernel_launch(void* const* d_in, const int* in_sizes, int n_in,
                              void* d_out, int out_size, void* d_ws, size_t ws_size,
                              hipStream_t stream) {
    (void)in_sizes; (void)n_in; (void)out_size; (void)ws_size;
    const int B = 2, T = 2048, D = 1024;
    const int M = B * T;  // 4096

    char* ws = (char*)d_ws;
    size_t off = 0;
    short* xb   = (short*)(ws + off); off += (size_t)M * D * 2;       // 8.4 MB
    short* wqkb = (short*)(ws + off); off += (size_t)3 * D * D * 2;   // 6.3 MB
    short* wob  = (short*)(ws + off); off += (size_t)D * D * 2;       // 2.1 MB
    short* qkv  = (short*)(ws + off); off += (size_t)M * 3 * D * 2;   // 25.2 MB
    short* attn = (short*)(ws + off); off += (size_t)M * D * 2;       // 8.4 MB

    convert_all<<<dim3(4096), 256, 0, stream>>>(
        (const float*)d_in[0], (const float*)d_in[1], (const float*)d_in[3],
        xb, wqkb, wob);

    gemm1_qkv<<<dim3(768), 256, 0, stream>>>(
        xb, wqkb, (const float*)d_in[2], qkv, M, 3 * D, D);
    attn_mfma<<<dim3(T / 64, 16, B), 256, 0, stream>>>(qkv, attn, B, T);
    gemm2_out<<<dim3(D / 128, M / 64), 256, 0, stream>>>(
        attn, wob, (const float*)d_in[4], (float*)d_out, M, D, D);
}